// Round 1
// baseline (293.988 us; speedup 1.0000x reference)
//
#include <hip/hip_runtime.h>
#include <math.h>

#define CIN   192
#define BATCH 8
#define HW    65536            // 256*256
#define HW4   16384            // float4 per (b,c) image
#define NBC   (BATCH * CIN)    // 1536
#define NDEG  3

__device__ __forceinline__ float gelu_exact(float x) {
    return 0.5f * x * (1.0f + erff(x * 0.70710678118654752f));
}
__device__ __forceinline__ float sigmoidf_(float x) {
    return 1.0f / (1.0f + expf(-x));
}

// Kernel 1: pooled[bc] = mean over H*W of x[bc,:,:]
__global__ __launch_bounds__(256) void pool_kernel(const float* __restrict__ x,
                                                   float* __restrict__ pooled) {
    const int bc = blockIdx.x;                       // 0..1535
    const float4* xp = reinterpret_cast<const float4*>(x) + (size_t)bc * HW4;
    const int t = threadIdx.x;
    float s = 0.0f;
#pragma unroll
    for (int i = 0; i < 64; ++i) {
        float4 v = xp[t + i * 256];
        s += (v.x + v.y) + (v.z + v.w);
    }
    // wave64 reduce
    for (int off = 32; off > 0; off >>= 1) s += __shfl_down(s, off, 64);
    __shared__ float ws[4];
    const int lane = t & 63, wid = t >> 6;
    if (lane == 0) ws[wid] = s;
    __syncthreads();
    if (t == 0) {
        float tot = (ws[0] + ws[1]) + (ws[2] + ws[3]);
        pooled[bc] = tot * (1.0f / 65536.0f);
    }
}

// Kernel 2: the whole tiny MLP in one block.
__global__ __launch_bounds__(256) void mlp_kernel(
    const float* __restrict__ pooled,
    const float* __restrict__ W1, const float* __restrict__ b1,
    const float* __restrict__ W2, const float* __restrict__ b2,
    const float* __restrict__ M1, const float* __restrict__ bm1,
    const float* __restrict__ M2, const float* __restrict__ bm2,
    float* __restrict__ mask, float* __restrict__ deg_out) {
    __shared__ float sp[NBC];          // pooled: 1536
    __shared__ float sh[BATCH * 128];  // h: 1024
    __shared__ float sd[BATCH * NDEG]; // deg_prob: 24
    __shared__ float sm[BATCH * 64];   // m: 512
    const int t = threadIdx.x;

    for (int i = t; i < NBC; i += 256) sp[i] = pooled[i];
    __syncthreads();

    // h = gelu(pooled @ W1 + b1)   (8 x 128)
    for (int i = t; i < BATCH * 128; i += 256) {
        const int b = i >> 7, j = i & 127;
        float acc = b1[j];
        const float* prow = &sp[b * CIN];
#pragma unroll 4
        for (int c = 0; c < CIN; ++c) acc += prow[c] * W1[c * 128 + j];
        sh[i] = gelu_exact(acc);
    }
    __syncthreads();

    // deg = sigmoid(h @ W2 + b2)   (8 x 3)
    if (t < BATCH * NDEG) {
        const int b = t / NDEG, d = t % NDEG;
        float acc = b2[d];
        const float* hrow = &sh[b * 128];
#pragma unroll 4
        for (int k = 0; k < 128; ++k) acc += hrow[k] * W2[k * NDEG + d];
        const float v = sigmoidf_(acc);
        sd[t] = v;
        deg_out[t] = v;                // second tuple output
    }
    __syncthreads();

    // m = gelu(deg @ M1 + bm1)   (8 x 64)
    for (int i = t; i < BATCH * 64; i += 256) {
        const int b = i >> 6, j = i & 63;
        float acc = bm1[j];
#pragma unroll
        for (int d = 0; d < NDEG; ++d) acc += sd[b * NDEG + d] * M1[d * 64 + j];
        sm[i] = gelu_exact(acc);
    }
    __syncthreads();

    // mask = sigmoid(m @ M2 + bm2)   (8 x 192)
    for (int i = t; i < NBC; i += 256) {
        const int b = i / CIN, c = i % CIN;
        float acc = bm2[c];
        const float* mrow = &sm[b * 64];
#pragma unroll 4
        for (int k = 0; k < 64; ++k) acc += mrow[k] * M2[k * CIN + c];
        mask[i] = sigmoidf_(acc);
    }
}

// Kernel 3: out[bc,h,w] = x[bc,h,w] * mask[bc]
__global__ __launch_bounds__(256) void scale_kernel(const float* __restrict__ x,
                                                    const float* __restrict__ mask,
                                                    float* __restrict__ out) {
    const int bc = blockIdx.x >> 3;                  // 8 chunks per channel image
    const int chunk = blockIdx.x & 7;
    const float mval = mask[bc];
    const size_t base = (size_t)bc * HW4 + (size_t)chunk * 2048;
    const float4* xp = reinterpret_cast<const float4*>(x) + base;
    float4* op = reinterpret_cast<float4*>(out) + base;
    const int t = threadIdx.x;
#pragma unroll
    for (int i = 0; i < 8; ++i) {
        float4 v = xp[t + i * 256];
        v.x *= mval; v.y *= mval; v.z *= mval; v.w *= mval;
        op[t + i * 256] = v;
    }
}

extern "C" void kernel_launch(void* const* d_in, const int* in_sizes, int n_in,
                              void* d_out, int out_size, void* d_ws, size_t ws_size,
                              hipStream_t stream) {
    const float* x   = (const float*)d_in[0];
    const float* W1  = (const float*)d_in[1];
    const float* b1  = (const float*)d_in[2];
    const float* W2  = (const float*)d_in[3];
    const float* b2  = (const float*)d_in[4];
    const float* M1  = (const float*)d_in[5];
    const float* bm1 = (const float*)d_in[6];
    const float* M2  = (const float*)d_in[7];
    const float* bm2 = (const float*)d_in[8];

    float* out0 = (float*)d_out;                       // 8*192*256*256 floats
    float* deg_out = out0 + (size_t)NBC * HW;          // 24 floats

    float* pooled = (float*)d_ws;                      // 1536 floats
    float* mask   = pooled + NBC;                      // 1536 floats

    pool_kernel<<<NBC, 256, 0, stream>>>(x, pooled);
    mlp_kernel<<<1, 256, 0, stream>>>(pooled, W1, b1, W2, b2, M1, bm1, M2, bm2,
                                      mask, deg_out);
    scale_kernel<<<NBC * 8, 256, 0, stream>>>(x, mask, out0);
}

// Round 2
// 221.668 us; speedup vs baseline: 1.3263x; 1.3263x over previous
//
#include <hip/hip_runtime.h>
#include <math.h>

#define CIN   192
#define BATCH 8
#define HW    65536            // 256*256
#define HW4   16384            // float4 per (b,c) image
#define NBC   (BATCH * CIN)    // 1536
#define NDEG  3

typedef float f4 __attribute__((ext_vector_type(4)));

__device__ __forceinline__ float gelu_exact(float x) {
    return 0.5f * x * (1.0f + erff(x * 0.70710678118654752f));
}
__device__ __forceinline__ float sigmoidf_(float x) {
    return 1.0f / (1.0f + expf(-x));
}

// Kernel 1: pooled[bc] = mean over H*W of x[bc,:,:]  (normal loads: prime L3)
__global__ __launch_bounds__(256) void pool_kernel(const float* __restrict__ x,
                                                   float* __restrict__ pooled) {
    const int bc = blockIdx.x;                       // 0..1535
    const f4* xp = reinterpret_cast<const f4*>(x) + (size_t)bc * HW4;
    const int t = threadIdx.x;
    float s = 0.0f;
#pragma unroll
    for (int i = 0; i < 64; ++i) {
        f4 v = xp[t + i * 256];
        s += (v.x + v.y) + (v.z + v.w);
    }
    // wave64 reduce
    for (int off = 32; off > 0; off >>= 1) s += __shfl_down(s, off, 64);
    __shared__ float ws[4];
    const int lane = t & 63, wid = t >> 6;
    if (lane == 0) ws[wid] = s;
    __syncthreads();
    if (t == 0) {
        float tot = (ws[0] + ws[1]) + (ws[2] + ws[3]);
        pooled[bc] = tot * (1.0f / 65536.0f);
    }
}

// Kernel 2: the whole tiny MLP in one block, weights staged in LDS.
__global__ __launch_bounds__(256) void mlp_kernel(
    const float* __restrict__ pooled,
    const float* __restrict__ W1, const float* __restrict__ b1,
    const float* __restrict__ W2, const float* __restrict__ b2,
    const float* __restrict__ M1, const float* __restrict__ bm1,
    const float* __restrict__ M2, const float* __restrict__ bm2,
    float* __restrict__ mask, float* __restrict__ deg_out) {
    __shared__ float w[CIN * 128];      // 98.3 KB: W1, then reused for M2
    __shared__ float sp[NBC];           // pooled: 1536
    __shared__ float sh[BATCH * 128];   // h: 1024
    __shared__ float sw2[128 * NDEG];   // W2: 384
    __shared__ float sM1[NDEG * 64];    // M1: 192
    __shared__ float sd[BATCH * NDEG];  // deg_prob: 24
    __shared__ float sm[BATCH * 64];    // m: 512
    const int t = threadIdx.x;

    // Stage pooled + W1 + W2 + M1 (coalesced)
    for (int i = t; i < NBC; i += 256) sp[i] = pooled[i];
    {
        const f4* src = reinterpret_cast<const f4*>(W1);
        f4* dst = reinterpret_cast<f4*>(w);
        for (int i = t; i < (CIN * 128) / 4; i += 256) dst[i] = src[i];
    }
    for (int i = t; i < 128 * NDEG; i += 256) sw2[i] = W2[i];
    if (t < NDEG * 64) sM1[t] = M1[t];
    __syncthreads();

    // h = gelu(pooled @ W1 + b1)   (8 x 128), all LDS
    for (int i = t; i < BATCH * 128; i += 256) {
        const int b = i >> 7, j = i & 127;
        float acc = b1[j];
        const float* prow = &sp[b * CIN];
#pragma unroll 8
        for (int c = 0; c < CIN; ++c) acc += prow[c] * w[c * 128 + j];
        sh[i] = gelu_exact(acc);
    }
    __syncthreads();   // layer1 done reading w — safe to overwrite below

    // Issue M2 -> w copy (consumed in layer 4, after next barrier)
    {
        const f4* src = reinterpret_cast<const f4*>(M2);
        f4* dst = reinterpret_cast<f4*>(w);
        for (int i = t; i < (64 * CIN) / 4; i += 256) dst[i] = src[i];
    }

    // deg = sigmoid(h @ W2 + b2)   (8 x 3)
    if (t < BATCH * NDEG) {
        const int b = t / NDEG, d = t % NDEG;
        float acc = b2[d];
        const float* hrow = &sh[b * 128];
#pragma unroll 8
        for (int k = 0; k < 128; ++k) acc += hrow[k] * sw2[k * NDEG + d];
        const float v = sigmoidf_(acc);
        sd[t] = v;
        deg_out[t] = v;                // second tuple output
    }
    __syncthreads();

    // m = gelu(deg @ M1 + bm1)   (8 x 64)
    for (int i = t; i < BATCH * 64; i += 256) {
        const int b = i >> 6, j = i & 63;
        float acc = bm1[j];
#pragma unroll
        for (int d = 0; d < NDEG; ++d) acc += sd[b * NDEG + d] * sM1[d * 64 + j];
        sm[i] = gelu_exact(acc);
    }
    __syncthreads();

    // mask = sigmoid(m @ M2 + bm2)   (8 x 192), M2 now in w
    for (int i = t; i < NBC; i += 256) {
        const int b = i / CIN, c = i % CIN;
        float acc = bm2[c];
        const float* mrow = &sm[b * 64];
#pragma unroll 8
        for (int k = 0; k < 64; ++k) acc += mrow[k] * w[k * CIN + c];
        mask[i] = sigmoidf_(acc);
    }
}

// Kernel 3: out[bc,h,w] = x[bc,h,w] * mask[bc]
// Reverse block order: pool streamed x forward, so the TAIL of x is L3-resident;
// read it first. Non-temporal ld/st so neither the output stream nor consumed x
// evicts not-yet-read x.
__global__ __launch_bounds__(256) void scale_kernel(const float* __restrict__ x,
                                                    const float* __restrict__ mask,
                                                    float* __restrict__ out) {
    const int rb = gridDim.x - 1 - blockIdx.x;       // reversed order
    const int bc = rb >> 3;                          // 8 chunks per channel image
    const int chunk = rb & 7;
    const float mval = mask[bc];
    const size_t base = (size_t)bc * HW4 + (size_t)chunk * 2048;
    const f4* xp = reinterpret_cast<const f4*>(x) + base;
    f4* op = reinterpret_cast<f4*>(out) + base;
    const int t = threadIdx.x;
#pragma unroll
    for (int i = 0; i < 8; ++i) {
        f4 v = __builtin_nontemporal_load(xp + t + i * 256);
        v *= mval;
        __builtin_nontemporal_store(v, op + t + i * 256);
    }
}

extern "C" void kernel_launch(void* const* d_in, const int* in_sizes, int n_in,
                              void* d_out, int out_size, void* d_ws, size_t ws_size,
                              hipStream_t stream) {
    const float* x   = (const float*)d_in[0];
    const float* W1  = (const float*)d_in[1];
    const float* b1  = (const float*)d_in[2];
    const float* W2  = (const float*)d_in[3];
    const float* b2  = (const float*)d_in[4];
    const float* M1  = (const float*)d_in[5];
    const float* bm1 = (const float*)d_in[6];
    const float* M2  = (const float*)d_in[7];
    const float* bm2 = (const float*)d_in[8];

    float* out0 = (float*)d_out;                       // 8*192*256*256 floats
    float* deg_out = out0 + (size_t)NBC * HW;          // 24 floats

    float* pooled = (float*)d_ws;                      // 1536 floats
    float* mask   = pooled + NBC;                      // 1536 floats

    pool_kernel<<<NBC, 256, 0, stream>>>(x, pooled);
    mlp_kernel<<<1, 256, 0, stream>>>(pooled, W1, b1, W2, b2, M1, bm1, M2, bm2,
                                      mask, deg_out);
    scale_kernel<<<NBC * 8, 256, 0, stream>>>(x, mask, out0);
}